// Round 1
// baseline (876.867 us; speedup 1.0000x reference)
//
#include <hip/hip_runtime.h>

#define BB 4
#define SS 2048
#define EE 512
#define HH 8
#define DD 64

// ---------------------------------------------------------------------------
// GEMM: C[M,N] = A[M,K] @ W[N,K]^T + bias[N]    (torch Linear, NT layout)
// 64x64 C tile per block, 256 threads, 4x4 accum per thread.
// LDS tiles stored transposed [k][m] with pad 68 (68*4=272 bytes, 16B-aligned
// rows) so inner-loop reads are float4 (ds_read_b128) and <=2-way bank
// aliased (free on CDNA4).
// blockIdx.z selects one of up to 3 (W, bias, C) sets (fused QKV).
// ---------------------------------------------------------------------------
__global__ __launch_bounds__(256)
void gemm_bias_nt(const float* __restrict__ A,
                  const float* __restrict__ W0, const float* __restrict__ b0,
                  float* __restrict__ C0,
                  const float* __restrict__ W1, const float* __restrict__ b1,
                  float* __restrict__ C1,
                  const float* __restrict__ W2, const float* __restrict__ b2,
                  float* __restrict__ C2,
                  int M, int N, int K)
{
    const float* W    = (blockIdx.z == 0) ? W0 : (blockIdx.z == 1) ? W1 : W2;
    const float* bias = (blockIdx.z == 0) ? b0 : (blockIdx.z == 1) ? b1 : b2;
    float*       C    = (blockIdx.z == 0) ? C0 : (blockIdx.z == 1) ? C1 : C2;

    __shared__ float As[64][68];  // [k][m]
    __shared__ float Ws[64][68];  // [k][n]

    const int tid = threadIdx.x;
    const int tx = tid & 15;       // 0..15 -> n sub-tile
    const int ty = tid >> 4;       // 0..15 -> m sub-tile
    const int m0 = blockIdx.x * 64;
    const int n0 = blockIdx.y * 64;

    const int lrow = tid >> 4;        // 0..15 staging row group
    const int lcol = (tid & 15) * 4;  // 0..60 staging k quad

    float acc[4][4] = {};

    for (int k0 = 0; k0 < K; k0 += 64) {
        #pragma unroll
        for (int i = 0; i < 4; ++i) {
            const int r = lrow + 16 * i;
            const float4 a = *reinterpret_cast<const float4*>(
                &A[(size_t)(m0 + r) * K + k0 + lcol]);
            As[lcol + 0][r] = a.x;
            As[lcol + 1][r] = a.y;
            As[lcol + 2][r] = a.z;
            As[lcol + 3][r] = a.w;
            const float4 w = *reinterpret_cast<const float4*>(
                &W[(size_t)(n0 + r) * K + k0 + lcol]);
            Ws[lcol + 0][r] = w.x;
            Ws[lcol + 1][r] = w.y;
            Ws[lcol + 2][r] = w.z;
            Ws[lcol + 3][r] = w.w;
        }
        __syncthreads();
        #pragma unroll 8
        for (int k = 0; k < 64; ++k) {
            const float4 av = *reinterpret_cast<const float4*>(&As[k][ty * 4]);
            const float4 wv = *reinterpret_cast<const float4*>(&Ws[k][tx * 4]);
            const float a[4] = {av.x, av.y, av.z, av.w};
            const float w[4] = {wv.x, wv.y, wv.z, wv.w};
            #pragma unroll
            for (int i = 0; i < 4; ++i)
                #pragma unroll
                for (int j = 0; j < 4; ++j)
                    acc[i][j] += a[i] * w[j];
        }
        __syncthreads();
    }

    const float4 bvec = *reinterpret_cast<const float4*>(&bias[n0 + tx * 4]);
    #pragma unroll
    for (int i = 0; i < 4; ++i) {
        const int m = m0 + ty * 4 + i;
        float4 out;
        out.x = acc[i][0] + bvec.x;
        out.y = acc[i][1] + bvec.y;
        out.z = acc[i][2] + bvec.z;
        out.w = acc[i][3] + bvec.w;
        *reinterpret_cast<float4*>(&C[(size_t)m * N + n0 + tx * 4]) = out;
    }
}

// ---------------------------------------------------------------------------
// Flash attention: one block per (q-tile of 64, head, batch).
// Q/K stored transposed [d][.] in LDS for float4 dot reads; V natural [k][d];
// P (scores) stored transposed [k][q] so PV reads are float4 along q.
// entangle[q]/sqrt(D) folded into the Q tile at load.
// Online softmax state (m, l, alpha) in LDS, O accumulator in registers.
// ---------------------------------------------------------------------------
__global__ __launch_bounds__(256)
void flash_attn(const float* __restrict__ Q, const float* __restrict__ K,
                const float* __restrict__ V, const float* __restrict__ ent,
                float* __restrict__ O)
{
    __shared__ float Qs[64][68];   // [d][q]  pre-scaled
    __shared__ float Ks[64][68];   // [d][k]
    __shared__ float Vs[64][68];   // [k][d]
    __shared__ float Ps[64][68];   // [k][q]
    __shared__ float mrow[64], lrow[64], arow[64];
    __shared__ float red[4][64];

    const int tid = threadIdx.x;
    const int tx = tid & 15;   // d / k sub-tile
    const int ty = tid >> 4;   // q sub-tile
    const int q0 = blockIdx.x * 64;
    const int h  = blockIdx.y;
    const int b  = blockIdx.z;

    const size_t bh_base = (size_t)b * SS * EE + (size_t)h * DD;

    const int lrow16 = tid >> 4;        // 0..15
    const int lcol   = (tid & 15) * 4;  // 0..60

    // Stage Q tile (transposed, scaled by entangle[q]*0.125)
    #pragma unroll
    for (int i = 0; i < 4; ++i) {
        const int q = lrow16 + 16 * i;
        const float e = ent[q0 + q] * 0.125f;
        const float4 v = *reinterpret_cast<const float4*>(
            &Q[bh_base + (size_t)(q0 + q) * EE + lcol]);
        Qs[lcol + 0][q] = v.x * e;
        Qs[lcol + 1][q] = v.y * e;
        Qs[lcol + 2][q] = v.z * e;
        Qs[lcol + 3][q] = v.w * e;
    }
    if (tid < 64) { mrow[tid] = -1e30f; lrow[tid] = 0.0f; }

    float o[4][4] = {};
    const int part = tid >> 6;   // 0..3
    const int qq   = tid & 63;

    for (int kt = 0; kt < SS / 64; ++kt) {
        const int kbase = kt * 64;
        // Stage K (transposed) and V (natural)
        #pragma unroll
        for (int i = 0; i < 4; ++i) {
            const int r = lrow16 + 16 * i;
            const float4 kv = *reinterpret_cast<const float4*>(
                &K[bh_base + (size_t)(kbase + r) * EE + lcol]);
            Ks[lcol + 0][r] = kv.x;
            Ks[lcol + 1][r] = kv.y;
            Ks[lcol + 2][r] = kv.z;
            Ks[lcol + 3][r] = kv.w;
            const float4 vv = *reinterpret_cast<const float4*>(
                &V[bh_base + (size_t)(kbase + r) * EE + lcol]);
            *reinterpret_cast<float4*>(&Vs[r][lcol]) = vv;
        }
        __syncthreads();

        // Scores: sc[i][j] = dot_d(Qs[:,ty*4+i], Ks[:,tx*4+j])  (scale folded)
        float sc[4][4] = {};
        #pragma unroll 8
        for (int d = 0; d < 64; ++d) {
            const float4 qv = *reinterpret_cast<const float4*>(&Qs[d][ty * 4]);
            const float4 kv = *reinterpret_cast<const float4*>(&Ks[d][tx * 4]);
            const float a[4] = {qv.x, qv.y, qv.z, qv.w};
            const float w[4] = {kv.x, kv.y, kv.z, kv.w};
            #pragma unroll
            for (int i = 0; i < 4; ++i)
                #pragma unroll
                for (int j = 0; j < 4; ++j)
                    sc[i][j] += a[i] * w[j];
        }
        // Write transposed: Ps[k][q]
        #pragma unroll
        for (int j = 0; j < 4; ++j) {
            float4 t;
            t.x = sc[0][j]; t.y = sc[1][j]; t.z = sc[2][j]; t.w = sc[3][j];
            *reinterpret_cast<float4*>(&Ps[tx * 4 + j][ty * 4]) = t;
        }
        __syncthreads();

        // Row max (4 partials per row)
        float pm = -1e30f;
        const int ks = part * 16;
        #pragma unroll
        for (int k = 0; k < 16; ++k)
            pm = fmaxf(pm, Ps[ks + k][qq]);
        red[part][qq] = pm;
        __syncthreads();
        if (tid < 64) {
            const float nm = fmaxf(mrow[tid],
                fmaxf(fmaxf(red[0][tid], red[1][tid]),
                      fmaxf(red[2][tid], red[3][tid])));
            arow[tid] = __expf(mrow[tid] - nm);
            mrow[tid] = nm;
        }
        __syncthreads();

        // Exponentiate in place + partial row sums
        const float mq = mrow[qq];
        float psum = 0.0f;
        #pragma unroll
        for (int k = 0; k < 16; ++k) {
            const float p = __expf(Ps[ks + k][qq] - mq);
            Ps[ks + k][qq] = p;
            psum += p;
        }
        red[part][qq] = psum;
        __syncthreads();
        if (tid < 64)
            lrow[tid] = lrow[tid] * arow[tid] +
                        red[0][tid] + red[1][tid] + red[2][tid] + red[3][tid];

        // PV accumulate (reads Ps/arow written before last sync; lrow unused here)
        #pragma unroll
        for (int i = 0; i < 4; ++i) {
            const float a = arow[ty * 4 + i];
            #pragma unroll
            for (int j = 0; j < 4; ++j)
                o[i][j] *= a;
        }
        #pragma unroll 8
        for (int k = 0; k < 64; ++k) {
            const float4 pv = *reinterpret_cast<const float4*>(&Ps[k][ty * 4]);
            const float4 vv = *reinterpret_cast<const float4*>(&Vs[k][tx * 4]);
            const float p[4] = {pv.x, pv.y, pv.z, pv.w};
            const float v[4] = {vv.x, vv.y, vv.z, vv.w};
            #pragma unroll
            for (int i = 0; i < 4; ++i)
                #pragma unroll
                for (int j = 0; j < 4; ++j)
                    o[i][j] += p[i] * v[j];
        }
        __syncthreads();  // protect Ks/Vs/Ps (and lrow epilogue read)
    }

    #pragma unroll
    for (int i = 0; i < 4; ++i) {
        const float il = 1.0f / lrow[ty * 4 + i];
        float4 t;
        t.x = o[i][0] * il;
        t.y = o[i][1] * il;
        t.z = o[i][2] * il;
        t.w = o[i][3] * il;
        *reinterpret_cast<float4*>(
            &O[bh_base + (size_t)(q0 + ty * 4 + i) * EE + tx * 4]) = t;
    }
}

extern "C" void kernel_launch(void* const* d_in, const int* in_sizes, int n_in,
                              void* d_out, int out_size, void* d_ws, size_t ws_size,
                              hipStream_t stream) {
    const float* x   = (const float*)d_in[0];
    const float* ent = (const float*)d_in[1];
    const float* Wq  = (const float*)d_in[2];
    const float* bq  = (const float*)d_in[3];
    const float* Wk  = (const float*)d_in[4];
    const float* bk  = (const float*)d_in[5];
    const float* Wv  = (const float*)d_in[6];
    const float* bv  = (const float*)d_in[7];
    const float* Wo  = (const float*)d_in[8];
    const float* bo  = (const float*)d_in[9];
    float* out = (float*)d_out;

    const size_t n_elem = (size_t)BB * SS * EE;  // 4*2048*512 = 4M floats
    float* Q  = (float*)d_ws;
    float* K  = Q + n_elem;
    float* V  = K + n_elem;
    float* AO = V + n_elem;

    const int M = BB * SS;  // 8192

    // Fused QKV projection
    dim3 gq(M / 64, EE / 64, 3);
    gemm_bias_nt<<<gq, 256, 0, stream>>>(x, Wq, bq, Q, Wk, bk, K, Wv, bv, V,
                                         M, EE, EE);
    // Flash attention
    dim3 ga(SS / 64, HH, BB);
    flash_attn<<<ga, 256, 0, stream>>>(Q, K, V, ent, AO);
    // Output projection
    dim3 go(M / 64, EE / 64, 1);
    gemm_bias_nt<<<go, 256, 0, stream>>>(AO, Wo, bo, out, Wo, bo, out,
                                         Wo, bo, out, M, EE, EE);
}

// Round 2
// 296.572 us; speedup vs baseline: 2.9567x; 2.9567x over previous
//
#include <hip/hip_runtime.h>
#include <hip/hip_bf16.h>

#define BB 4
#define SS 2048
#define EE 512
#define HH 8
#define DD 64

typedef __attribute__((ext_vector_type(8))) short bf16x8;   // 8 bf16 = 4 VGPRs
typedef __attribute__((ext_vector_type(4))) float f32x4;

__device__ __forceinline__ unsigned short f2bf(float f) {
    __hip_bfloat16 h = __float2bfloat16(f);   // round-to-nearest
    return *reinterpret_cast<unsigned short*>(&h);
}

// ---------------------------------------------------------------------------
// fp32 -> bf16 cast, 5 tensors in one launch (blockIdx.y selects).
// ---------------------------------------------------------------------------
__global__ __launch_bounds__(256)
void cast_all(const float* __restrict__ x,
              const float* __restrict__ wq, const float* __restrict__ wk,
              const float* __restrict__ wv, const float* __restrict__ wo,
              unsigned short* __restrict__ xb,
              unsigned short* __restrict__ wqb, unsigned short* __restrict__ wkb,
              unsigned short* __restrict__ wvb, unsigned short* __restrict__ wob)
{
    const int t = blockIdx.y;
    const float* src; unsigned short* dst; int n4;
    switch (t) {
        case 0: src = x;  dst = xb;  n4 = (BB*SS*EE)/4; break;
        case 1: src = wq; dst = wqb; n4 = (EE*EE)/4; break;
        case 2: src = wk; dst = wkb; n4 = (EE*EE)/4; break;
        case 3: src = wv; dst = wvb; n4 = (EE*EE)/4; break;
        default: src = wo; dst = wob; n4 = (EE*EE)/4; break;
    }
    const int i = blockIdx.x * 256 + threadIdx.x;
    if (i >= n4) return;
    const float4 v = reinterpret_cast<const float4*>(src)[i];
    ushort4 o;
    o.x = f2bf(v.x); o.y = f2bf(v.y); o.z = f2bf(v.z); o.w = f2bf(v.w);
    reinterpret_cast<ushort4*>(dst)[i] = o;
}

// ---------------------------------------------------------------------------
// MFMA GEMM: C[M,N] = bf16(A[M,K]) @ bf16(W[N,K])^T + bias[N]
// 128x128 tile, 256 threads = 4 waves (2x2 of 64x64), 16x16x32 bf16 MFMA,
// BK=32. LDS rows padded to 40 shorts (80 B): frag reads <=2-way bank alias.
// blockIdx.z selects (W, bias, C) set for fused QKV.
// ---------------------------------------------------------------------------
#define GPAD 40

template<typename OutT>
__global__ __launch_bounds__(256)
void gemm_mfma_nt(const unsigned short* __restrict__ A,
                  const unsigned short* __restrict__ W0, const float* __restrict__ b0, OutT* __restrict__ C0,
                  const unsigned short* __restrict__ W1, const float* __restrict__ b1, OutT* __restrict__ C1,
                  const unsigned short* __restrict__ W2, const float* __restrict__ b2, OutT* __restrict__ C2,
                  int M, int N, int K)
{
    const unsigned short* W = (blockIdx.z == 0) ? W0 : (blockIdx.z == 1) ? W1 : W2;
    const float* bias       = (blockIdx.z == 0) ? b0 : (blockIdx.z == 1) ? b1 : b2;
    OutT* C                 = (blockIdx.z == 0) ? C0 : (blockIdx.z == 1) ? C1 : C2;

    __shared__ unsigned short As[128 * GPAD];
    __shared__ unsigned short Bs[128 * GPAD];

    const int tid  = threadIdx.x;
    const int wave = tid >> 6, lane = tid & 63;
    const int quad = lane >> 4, r16 = lane & 15;
    const int m0 = blockIdx.x * 128, n0 = blockIdx.y * 128;
    const int wm0 = (wave >> 1) * 64, wn0 = (wave & 1) * 64;

    f32x4 acc[4][4];
    const f32x4 zero = {0.f, 0.f, 0.f, 0.f};
    #pragma unroll
    for (int i = 0; i < 4; ++i)
        #pragma unroll
        for (int j = 0; j < 4; ++j) acc[i][j] = zero;

    for (int k0 = 0; k0 < K; k0 += 32) {
        __syncthreads();   // previous iteration's frag reads done
        #pragma unroll
        for (int i = 0; i < 2; ++i) {
            const int c = tid + 256 * i;
            const int row = c >> 2, col = (c & 3) * 8;
            *reinterpret_cast<float4*>(&As[row * GPAD + col]) =
                *reinterpret_cast<const float4*>(&A[(size_t)(m0 + row) * K + k0 + col]);
            *reinterpret_cast<float4*>(&Bs[row * GPAD + col]) =
                *reinterpret_cast<const float4*>(&W[(size_t)(n0 + row) * K + k0 + col]);
        }
        __syncthreads();
        bf16x8 af[4], bfr[4];
        #pragma unroll
        for (int t = 0; t < 4; ++t) {
            af[t]  = *reinterpret_cast<bf16x8*>(&As[(wm0 + t * 16 + r16) * GPAD + quad * 8]);
            bfr[t] = *reinterpret_cast<bf16x8*>(&Bs[(wn0 + t * 16 + r16) * GPAD + quad * 8]);
        }
        #pragma unroll
        for (int mt = 0; mt < 4; ++mt)
            #pragma unroll
            for (int nt = 0; nt < 4; ++nt)
                acc[mt][nt] = __builtin_amdgcn_mfma_f32_16x16x32_bf16(
                    af[mt], bfr[nt], acc[mt][nt], 0, 0, 0);
    }

    // Epilogue. C/D layout: col = lane&15, row = quad*4 + reg (m89-verified).
    #pragma unroll
    for (int mt = 0; mt < 4; ++mt) {
        #pragma unroll
        for (int nt = 0; nt < 4; ++nt) {
            const int col = n0 + wn0 + nt * 16 + r16;
            const float bv = bias[col];
            #pragma unroll
            for (int r = 0; r < 4; ++r) {
                const int row = m0 + wm0 + mt * 16 + quad * 4 + r;
                const float v = acc[mt][nt][r] + bv;
                if constexpr (sizeof(OutT) == 2)
                    C[(size_t)row * N + col] = (OutT)f2bf(v);
                else
                    C[(size_t)row * N + col] = (OutT)v;
            }
        }
    }
}

// ---------------------------------------------------------------------------
// MFMA flash attention. Block = 64 q-rows x (head,batch); 4 waves, each owns
// 16 q-rows. QK^T and PV via 16x16x32 bf16 MFMA; fp32 online softmax with
// state in registers (replicated across each 16-lane quad group).
// P: C/D layout -> LDS -> A-operand layout round trip (m120 pattern).
// V transposed in LDS for the B operand. All LDS rows padded to 72 shorts.
// ---------------------------------------------------------------------------
#define APAD 72

__global__ __launch_bounds__(256)
void attn_mfma(const unsigned short* __restrict__ Q,
               const unsigned short* __restrict__ K,
               const unsigned short* __restrict__ V,
               const float* __restrict__ ent,
               unsigned short* __restrict__ O)
{
    __shared__ unsigned short Qs[64 * APAD];     // [q][d]
    __shared__ unsigned short Ks[64 * APAD];     // [k][d]
    __shared__ unsigned short Vt[64 * APAD];     // [d][k]
    __shared__ unsigned short Ps[4][16 * APAD];  // per-wave [q16][k64]

    const int tid  = threadIdx.x;
    const int wave = tid >> 6, lane = tid & 63;
    const int quad = lane >> 4, r16 = lane & 15;
    const int q0 = blockIdx.x * 64;
    const int h  = blockIdx.y, b = blockIdx.z;
    const size_t base = (size_t)b * SS * EE + (size_t)h * DD;

    // Stage Q tile: 64 rows x 64 bf16 (128 B) = 512 x 16 B chunks.
    #pragma unroll
    for (int i = 0; i < 2; ++i) {
        const int c = tid + 256 * i;
        const int row = c >> 3, cc = c & 7;
        *reinterpret_cast<float4*>(&Qs[row * APAD + cc * 8]) =
            *reinterpret_cast<const float4*>(&Q[base + (size_t)(q0 + row) * EE + cc * 8]);
    }

    float eq[4];
    #pragma unroll
    for (int r = 0; r < 4; ++r)
        eq[r] = ent[q0 + wave * 16 + quad * 4 + r] * 0.125f;

    float m_i[4] = {-1e30f, -1e30f, -1e30f, -1e30f};
    float l_i[4] = {0.f, 0.f, 0.f, 0.f};
    f32x4 o_acc[4];
    const f32x4 zero = {0.f, 0.f, 0.f, 0.f};
    #pragma unroll
    for (int dt = 0; dt < 4; ++dt) o_acc[dt] = zero;

    for (int kt = 0; kt < SS / 64; ++kt) {
        const int kb = kt * 64;
        __syncthreads();   // all reads of Ks/Vt/Ps from prev tile complete
        // Stage K [k][d]
        #pragma unroll
        for (int i = 0; i < 2; ++i) {
            const int c = tid + 256 * i;
            const int row = c >> 3, cc = c & 7;
            *reinterpret_cast<float4*>(&Ks[row * APAD + cc * 8]) =
                *reinterpret_cast<const float4*>(&K[base + (size_t)(kb + row) * EE + cc * 8]);
        }
        // Stage V transposed -> Vt[d][k]
        #pragma unroll
        for (int i = 0; i < 2; ++i) {
            const int r  = i * 32 + (tid >> 3);
            const int d0 = (tid & 7) * 8;
            unsigned short tmp[8];
            *reinterpret_cast<float4*>(tmp) =
                *reinterpret_cast<const float4*>(&V[base + (size_t)(kb + r) * EE + d0]);
            #pragma unroll
            for (int j = 0; j < 8; ++j) Vt[(d0 + j) * APAD + r] = tmp[j];
        }
        __syncthreads();

        // QK^T: a = Q[m=r16][d], b = K[n=r16][d]; 2 MFMAs per 16-wide k tile.
        f32x4 s[4];
        #pragma unroll
        for (int tn = 0; tn < 4; ++tn) s[tn] = zero;
        bf16x8 qf0 = *reinterpret_cast<bf16x8*>(&Qs[(wave * 16 + r16) * APAD + quad * 8]);
        bf16x8 qf1 = *reinterpret_cast<bf16x8*>(&Qs[(wave * 16 + r16) * APAD + 32 + quad * 8]);
        #pragma unroll
        for (int tn = 0; tn < 4; ++tn) {
            bf16x8 kf0 = *reinterpret_cast<bf16x8*>(&Ks[(tn * 16 + r16) * APAD + quad * 8]);
            bf16x8 kf1 = *reinterpret_cast<bf16x8*>(&Ks[(tn * 16 + r16) * APAD + 32 + quad * 8]);
            s[tn] = __builtin_amdgcn_mfma_f32_16x16x32_bf16(qf0, kf0, s[tn], 0, 0, 0);
            s[tn] = __builtin_amdgcn_mfma_f32_16x16x32_bf16(qf1, kf1, s[tn], 0, 0, 0);
        }

        // Online softmax. Row q = quad*4+r owned by the 16 lanes of this quad.
        float p[4][4], alpha[4];
        #pragma unroll
        for (int r = 0; r < 4; ++r) {
            const float s0 = s[0][r] * eq[r], s1 = s[1][r] * eq[r];
            const float s2 = s[2][r] * eq[r], s3 = s[3][r] * eq[r];
            float mx = fmaxf(fmaxf(s0, s1), fmaxf(s2, s3));
            #pragma unroll
            for (int d = 1; d < 16; d <<= 1)
                mx = fmaxf(mx, __shfl_xor(mx, d, 64));
            const float mn = fmaxf(m_i[r], mx);
            alpha[r] = __expf(m_i[r] - mn);
            m_i[r] = mn;
            const float p0 = __expf(s0 - mn), p1 = __expf(s1 - mn);
            const float p2 = __expf(s2 - mn), p3 = __expf(s3 - mn);
            float ps = p0 + p1 + p2 + p3;
            #pragma unroll
            for (int d = 1; d < 16; d <<= 1)
                ps += __shfl_xor(ps, d, 64);
            l_i[r] = l_i[r] * alpha[r] + ps;
            p[0][r] = p0; p[1][r] = p1; p[2][r] = p2; p[3][r] = p3;
        }

        // Rescale O, write P (C/D layout -> LDS [q][k]).
        #pragma unroll
        for (int dt = 0; dt < 4; ++dt)
            #pragma unroll
            for (int r = 0; r < 4; ++r)
                o_acc[dt][r] *= alpha[r];
        unsigned short* pw = &Ps[wave][0];
        #pragma unroll
        for (int tn = 0; tn < 4; ++tn)
            #pragma unroll
            for (int r = 0; r < 4; ++r)
                pw[(quad * 4 + r) * APAD + tn * 16 + r16] = f2bf(p[tn][r]);
        __syncthreads();   // P visible (and ordered) before A-layout reads

        // PV: a = P[m=r16][k], b = Vt[n=d=r16][k].
        bf16x8 pf0 = *reinterpret_cast<bf16x8*>(&pw[r16 * APAD + quad * 8]);
        bf16x8 pf1 = *reinterpret_cast<bf16x8*>(&pw[r16 * APAD + 32 + quad * 8]);
        #pragma unroll
        for (int dt = 0; dt < 4; ++dt) {
            bf16x8 vf0 = *reinterpret_cast<bf16x8*>(&Vt[(dt * 16 + r16) * APAD + quad * 8]);
            bf16x8 vf1 = *reinterpret_cast<bf16x8*>(&Vt[(dt * 16 + r16) * APAD + 32 + quad * 8]);
            o_acc[dt] = __builtin_amdgcn_mfma_f32_16x16x32_bf16(pf0, vf0, o_acc[dt], 0, 0, 0);
            o_acc[dt] = __builtin_amdgcn_mfma_f32_16x16x32_bf16(pf1, vf1, o_acc[dt], 0, 0, 0);
        }
    }

    // Epilogue: O[q][h*64+d] as bf16 for the output projection.
    #pragma unroll
    for (int dt = 0; dt < 4; ++dt) {
        #pragma unroll
        for (int r = 0; r < 4; ++r) {
            const float v = o_acc[dt][r] / l_i[r];
            O[base + (size_t)(q0 + wave * 16 + quad * 4 + r) * EE + dt * 16 + r16] = f2bf(v);
        }
    }
}

extern "C" void kernel_launch(void* const* d_in, const int* in_sizes, int n_in,
                              void* d_out, int out_size, void* d_ws, size_t ws_size,
                              hipStream_t stream) {
    const float* x   = (const float*)d_in[0];
    const float* ent = (const float*)d_in[1];
    const float* Wq  = (const float*)d_in[2];
    const float* bq  = (const float*)d_in[3];
    const float* Wk  = (const float*)d_in[4];
    const float* bk  = (const float*)d_in[5];
    const float* Wv  = (const float*)d_in[6];
    const float* bv  = (const float*)d_in[7];
    const float* Wo  = (const float*)d_in[8];
    const float* bo  = (const float*)d_in[9];
    float* out = (float*)d_out;

    const size_t n_x = (size_t)BB * SS * EE;   // 4 Mi elements
    const size_t n_w = (size_t)EE * EE;        // 256 Ki elements

    unsigned short* xb  = (unsigned short*)d_ws;
    unsigned short* wqb = xb + n_x;
    unsigned short* wkb = wqb + n_w;
    unsigned short* wvb = wkb + n_w;
    unsigned short* wob = wvb + n_w;
    unsigned short* Qb  = wob + n_w;
    unsigned short* Kb  = Qb + n_x;
    unsigned short* Vb  = Kb + n_x;
    unsigned short* AOb = Vb + n_x;

    const int M = BB * SS;  // 8192

    dim3 gc(4096, 5, 1);
    cast_all<<<gc, 256, 0, stream>>>(x, Wq, Wk, Wv, Wo, xb, wqb, wkb, wvb, wob);

    dim3 gq(M / 128, EE / 128, 3);
    gemm_mfma_nt<unsigned short><<<gq, 256, 0, stream>>>(
        xb, wqb, bq, Qb, wkb, bk, Kb, wvb, bv, Vb, M, EE, EE);

    dim3 ga(SS / 64, HH, BB);
    attn_mfma<<<ga, 256, 0, stream>>>(Qb, Kb, Vb, ent, AOb);

    dim3 go(M / 128, EE / 128, 1);
    gemm_mfma_nt<float><<<go, 256, 0, stream>>>(
        AOb, wob, bo, out, wob, bo, out, wob, bo, out, M, EE, EE);
}